// Round 8
// baseline (226682.373 us; speedup 1.0000x reference)
//
#include <hip/hip_runtime.h>
#include <math.h>

// Problem constants
#define Bz 512
#define Sz 128
#define Dz 128
#define Hz 1024
#define Lz 128
#define NSUB 4

#define GRID 256
#define BLOCK 512
#define NGRP 16   // independent groups (32 batch rows each)
#define GBLK 16   // blocks per group

typedef _Float16 half8 __attribute__((ext_vector_type(8)));
typedef float floatx4 __attribute__((ext_vector_type(4)));
typedef unsigned long long u64;

#define MFMA16(a, b, c) __builtin_amdgcn_mfma_f32_16x16x32_f16(a, b, c, 0, 0, 0)

// ---- old-path (GRU/proj) LDS layout: unchanged from R5 ----
#define AHI_O 0
#define ALO_D 4096
#define BHI_O 8192
#define BLO_D 8192
#define CHUNK_HALFS 24576
// ---- fast-path LDS: 2 x 8192-half buffers (A only: hi at +0, lo at +4096)

enum { EPI_NONE = 0, EPI_Y = 1, EPI_H = 2 };

// dopri5 tableau row i+1 (input coeffs of stage i+1). Row 5 == 5th-order b
// weights (FSAL): h_next = y_6; stage-7 f-eval is dead and skipped.
__constant__ float DPA_C[6][6] = {
  {0.2f, 0.f, 0.f, 0.f, 0.f, 0.f},
  {0.075f, 0.225f, 0.f, 0.f, 0.f, 0.f},
  {44.f/45.f, -56.f/15.f, 32.f/9.f, 0.f, 0.f, 0.f},
  {19372.f/6561.f, -25360.f/2187.f, 64448.f/6561.f, -212.f/729.f, 0.f, 0.f},
  {9017.f/3168.f, -355.f/33.f, 46732.f/5247.f, 49.f/176.f, -5103.f/18656.f, 0.f},
  {35.f/384.f, 0.f, 500.f/1113.f, 125.f/192.f, -2187.f/6784.f, 11.f/84.f},
};

struct KArgs {
  const float *x, *t, *w_ih, *w_hh, *b_ih, *b_hh;
  const float *w0, *b0, *w1, *b1, *w2, *b2, *mu_w, *mu_b, *lv_w, *lv_b;
  float* out;
  float *h, *y, *t1, *t2, *gi, *gh;
  unsigned* bar;
};

// ---- IF$-level (cross-XCD coherent) accesses: relaxed agent atomics bypass
// L1+L2 with NO cache-wiping fences. Weights stay in L2.
__device__ __forceinline__ float2 ldc2(const float* p) {
  u64 v = __hip_atomic_load((u64*)p, __ATOMIC_RELAXED, __HIP_MEMORY_SCOPE_AGENT);
  union { u64 u; float2 f; } c; c.u = v; return c.f;
}
__device__ __forceinline__ float ldc1(const float* p) {
  unsigned v = __hip_atomic_load((unsigned*)p, __ATOMIC_RELAXED, __HIP_MEMORY_SCOPE_AGENT);
  union { unsigned u; float f; } c; c.u = v; return c.f;
}
__device__ __forceinline__ void stc1(float* p, float f) {
  union { float f; unsigned u; } c; c.f = f;
  __hip_atomic_store((unsigned*)p, c.u, __ATOMIC_RELAXED, __HIP_MEMORY_SCOPE_AGENT);
}

// Group barrier (16 blocks): equality-poll (poison-safe, no init needed).
// Producer waves drain stores (vmcnt) before signaling; relaxed flags ->
// no L2 invalidation anywhere.
__device__ __forceinline__ void gbar(unsigned* gb, int jj, unsigned e) {
  asm volatile("s_waitcnt vmcnt(0) lgkmcnt(0)" ::: "memory");
  __syncthreads();
  const int t = threadIdx.x;
  if (jj == 0) {
    if (t >= 1 && t < GBLK) {
      while (__hip_atomic_load(&gb[t], __ATOMIC_RELAXED, __HIP_MEMORY_SCOPE_AGENT) != e)
        __builtin_amdgcn_s_sleep(1);
    }
    __syncthreads();
    if (t == 0)
      __hip_atomic_store(&gb[32], e, __ATOMIC_RELAXED, __HIP_MEMORY_SCOPE_AGENT);
  } else {
    if (t == 0) {
      __hip_atomic_store(&gb[jj], e, __ATOMIC_RELAXED, __HIP_MEMORY_SCOPE_AGENT);
      while (__hip_atomic_load(&gb[32], __ATOMIC_RELAXED, __HIP_MEMORY_SCOPE_AGENT) != e)
        __builtin_amdgcn_s_sleep(1);
    }
    __syncthreads();
  }
}

__device__ __forceinline__ void split8(float4 a, float4 b, half8& h, half8& l) {
  float v[8] = {a.x, a.y, a.z, a.w, b.x, b.y, b.z, b.w};
#pragma unroll
  for (int i = 0; i < 8; ++i) {
    _Float16 hh = (_Float16)v[i];
    h[i] = hh;
    l[i] = (_Float16)((v[i] - (float)hh) * 2048.0f);
  }
}

// ---- FAST PATH: one 32x64 tile, K=1024. A via IF$->in-register split->LDS
// (frag-major, conflict-free). B: per-wave DIRECT fp32 loads from the original
// weight (L2-resident, read-only input) + in-register split — the R3/R4/R5-
// proven mechanism; no ws round-trip. 4 MFMA products (~2^-24-grade recomb).
__device__ __forceinline__ void mfma_tile_fast(
    const float* __restrict__ A, const float* __restrict__ W,
    const float* __restrict__ bias,
    float* __restrict__ Yd,
    int act, int epi, int stage, float hs,
    const float* __restrict__ hbuf,
    floatx4& K0, floatx4& K1, floatx4& K2, floatx4& K3, floatx4& K4,
    floatx4& Hc,
    int row0, int col0, _Float16* __restrict__ lds)
{
  const int tid = threadIdx.x;
  const int ln = tid & 63, l16 = ln & 15, qd = ln >> 4;
  const int wv = tid >> 6, wr = wv >> 2, wc = wv & 3;

  // A staging: wave wv owns (k32 sc=wv&3, rowgroup srg=wv>>2); lane ln -> slot ln
  const int sc = wv & 3, srg = wv >> 2;
  const float* gA = A + (size_t)(row0 + (srg << 4) + l16) * Hz + (sc << 5) + (qd << 3);
  const int sidx = ((((sc << 1) + srg) << 6) + ln) * 8;   // hi offset in buffer

  // B direct: lane (l16,qd) owns row n = col0 + wc*16 + l16, k-base qd*8
  const float* gBw = W + (size_t)(col0 + (wc << 4) + l16) * Hz + (qd << 3);

  float av[8];
  auto ldA = [&](int c) {
    const float* p = gA + (c << 7);
#pragma unroll
    for (int i = 0; i < 4; ++i) {
      float2 t = ldc2(p + 2 * i);
      av[2 * i] = t.x; av[2 * i + 1] = t.y;
    }
  };
  auto stA = [&](int buf) {
    _Float16* d = lds + (buf << 13) + sidx;
    half8 h, l;
#pragma unroll
    for (int i = 0; i < 8; ++i) {
      _Float16 hh = (_Float16)av[i];
      h[i] = hh;
      l[i] = (_Float16)((av[i] - (float)hh) * 2048.0f);
    }
    *(half8*)d = h;
    *(half8*)(d + 4096) = l;
  };
  auto ldBf = [&](int c, float4* bq) {
#pragma unroll
    for (int kq = 0; kq < 4; ++kq) {
      bq[2 * kq]     = *(const float4*)(gBw + (c << 7) + (kq << 5));
      bq[2 * kq + 1] = *(const float4*)(gBw + (c << 7) + (kq << 5) + 4);
    }
  };

  floatx4 Phh = {0,0,0,0}, Phl = {0,0,0,0}, Plh = {0,0,0,0}, Pll = {0,0,0,0};

  float4 bq[8];
  ldBf(0, bq);                   // B chunk 0 in flight early
  ldA(0);
  __syncthreads();               // prior phase's LDS readers done
  stA(0);
  ldA(1);

#pragma unroll
  for (int c = 0; c < 8; ++c) {
    __syncthreads();             // buf[c&1] stores visible; buf[c^1] free
    const int cur = c & 1;
    if (c + 1 < 8) {
      stA(cur ^ 1);              // regs (chunk c+1, loaded a full iter ago)
      if (c + 2 < 8) ldA(c + 2);
    }
    float4 bn[8];
    if (c + 1 < 8) ldBf(c + 1, bn);   // next B in flight during this chunk
    const _Float16* rb = lds + (cur << 13);
#pragma unroll
    for (int kq = 0; kq < 4; ++kq) {
      half8 bh, bl;
      split8(bq[2 * kq], bq[2 * kq + 1], bh, bl);
      const int ao = ((((kq << 1) + wr) << 6) + ln) * 8;
      half8 ah = *(const half8*)(rb + ao);
      half8 al = *(const half8*)(rb + ao + 4096);
      Phh = MFMA16(ah, bh, Phh);
      Phl = MFMA16(ah, bl, Phl);
      Plh = MFMA16(al, bh, Plh);
      Pll = MFMA16(al, bl, Pll);
    }
    if (c + 1 < 8) {
#pragma unroll
      for (int i = 0; i < 8; ++i) bq[i] = bn[i];   // SSA-renamed (unrolled)
    }
  }

  // Epilogue. C/D layout: col = lane&15, row = (lane>>4)*4 + i (m89-verified)
  const int col   = col0 + (wc << 4) + l16;
  const int rbase = row0 + (wr << 4) + (qd << 2);
  const float bb = bias[col];
#pragma unroll
  for (int i = 0; i < 4; ++i) {
    float v = Phh[i] + (Phl[i] + Plh[i]) * (1.0f/2048.0f)
            + Pll[i] * (1.0f/4194304.0f) + bb;
    if (act) v = tanhf(v);
    const size_t off = (size_t)(rbase + i) * Hz + col;
    if (epi == EPI_NONE) {
      stc1(&Yd[off], v);
    } else {
      if (stage == 0) Hc[i] = ldc1(&hbuf[off]);
      float yv = Hc[i];
      const float* DP = DPA_C[stage];
      if (stage > 0) yv = fmaf(hs * DP[0], K0[i], yv);
      if (stage > 1) { float c1 = DP[1]; if (c1 != 0.f) yv = fmaf(hs * c1, K1[i], yv); }
      if (stage > 2) yv = fmaf(hs * DP[2], K2[i], yv);
      if (stage > 3) yv = fmaf(hs * DP[3], K3[i], yv);
      if (stage > 4) yv = fmaf(hs * DP[4], K4[i], yv);
      yv = fmaf(hs * DP[stage], v, yv);
      if      (stage == 0) K0[i] = v;
      else if (stage == 1) K1[i] = v;
      else if (stage == 2) K2[i] = v;
      else if (stage == 3) K3[i] = v;
      else if (stage == 4) K4[i] = v;
      stc1(&Yd[off], yv);
    }
  }
}

// ---- OLD PATH (R5, proven): used for GRU gates, wih, mu/lv ----
template<bool ACo>
__device__ __forceinline__ void mfma_tile(
    const float* __restrict__ A, int lda, int K,
    const float* __restrict__ W, const float* __restrict__ bias,
    float* __restrict__ Cf, int ldc,
    int row0, int col0, _Float16* __restrict__ lds)
{
  const int tid = threadIdx.x;
  const int ln  = tid & 63;
  const int l16 = ln & 15;
  const int qd  = ln >> 4;
  const int wv  = tid >> 6;
  const int wr  = wv >> 2;
  const int wc  = wv & 3;

  const int an   = tid >> 4;
  const int an15 = an & 15, ang = an >> 4;
  const int seg  = tid & 15;
  const int c_ = seg >> 2, q_ = seg & 3;
  const int ua = q_ * 16 + (an15 ^ (((q_ ^ c_) & 1) << 2));
  const int aoff  = AHI_O + (((c_ * 2 + ang) * 64 + ua) << 3);
  const int boff0 = BHI_O + (((c_ * 4 + ang) * 64 + ua) << 3);
  const int boff1 = BHI_O + (((c_ * 4 + 2 + ang) * 64 + ua) << 3);

  const float* gA  = A + (size_t)(row0 + an) * lda + (seg << 3);
  const float* gB0 = W + (size_t)(col0 + an) * K + (seg << 3);
  const float* gB1 = W + (size_t)(col0 + 32 + an) * K + (seg << 3);
  const int NC = K >> 7;

  floatx4 Phh = {0,0,0,0}, Phl = {0,0,0,0}, Plh = {0,0,0,0}, Pll = {0,0,0,0};

  float4 ra0, ra1, rb00, rb01, rb10, rb11;
  auto load6 = [&](int kk) {
    if (ACo) {
      float2 a0 = ldc2(gA + kk),     a1 = ldc2(gA + kk + 2);
      float2 a2 = ldc2(gA + kk + 4), a3 = ldc2(gA + kk + 6);
      ra0 = make_float4(a0.x, a0.y, a1.x, a1.y);
      ra1 = make_float4(a2.x, a2.y, a3.x, a3.y);
    } else {
      ra0 = *(const float4*)(gA + kk);
      ra1 = *(const float4*)(gA + kk + 4);
    }
    rb00 = *(const float4*)(gB0 + kk); rb01 = *(const float4*)(gB0 + kk + 4);
    rb10 = *(const float4*)(gB1 + kk); rb11 = *(const float4*)(gB1 + kk + 4);
  };
  auto store6 = [&]() {
    half8 h, l;
    split8(ra0, ra1, h, l);
    *(half8*)&lds[aoff] = h;  *(half8*)&lds[aoff + ALO_D] = l;
    split8(rb00, rb01, h, l);
    *(half8*)&lds[boff0] = h; *(half8*)&lds[boff0 + BLO_D] = l;
    split8(rb10, rb11, h, l);
    *(half8*)&lds[boff1] = h; *(half8*)&lds[boff1 + BLO_D] = l;
  };

  load6(0);
  __syncthreads();
  store6();
  if (NC > 1) load6(128);

  for (int c = 0; c < NC; ++c) {
    __syncthreads();
#pragma unroll
    for (int kq = 0; kq < 4; ++kq) {
      const int lnw = ln ^ (((qd ^ kq) & 1) << 2);
      const int ab = ((kq * 2 + wr) * 64 + lnw) << 3;
      const int bb = BHI_O + (((kq * 4 + wc) * 64 + lnw) << 3);
      half8 ah = *(const half8*)&lds[ab];
      half8 al = *(const half8*)&lds[ab + ALO_D];
      half8 bh = *(const half8*)&lds[bb];
      half8 bl = *(const half8*)&lds[bb + BLO_D];
      Phh = MFMA16(ah, bh, Phh);
      Phl = MFMA16(ah, bl, Phl);
      Plh = MFMA16(al, bh, Plh);
      Pll = MFMA16(al, bl, Pll);
    }
    __syncthreads();
    if (c + 1 < NC) {
      store6();
      if (c + 2 < NC) load6((c + 2) << 7);
    }
  }

  const int col   = col0 + (wc << 4) + l16;
  const int rbase = row0 + (wr << 4) + (qd << 2);
  const float bb = bias[col];
#pragma unroll
  for (int i = 0; i < 4; ++i) {
    float v = Phh[i] + (Phl[i] + Plh[i]) * (1.0f/2048.0f)
            + Pll[i] * (1.0f/4194304.0f) + bb;
    const size_t off = (size_t)(rbase + i) * ldc + col;
    stc1(&Cf[off], v);
  }
}

template<bool ACo>
__device__ __forceinline__ void run_phase(
    const float* A, int lda, int K,
    const float* W, const float* bias, int N,
    float* Cf, int ldc, int g, int jj, _Float16* lds)
{
  const int tilesN = N >> 6;
  const int row0 = g << 5;
  if (tilesN >= GBLK) {
    const int tn0 = ((jj & 7) << 1) | (jj >> 3);
    for (int i = 0; i < (tilesN >> 4); ++i)
      mfma_tile<ACo>(A, lda, K, W, bias, Cf, ldc,
                     row0, (tn0 + (i << 4)) << 6, lds);
  } else {
    if (jj < tilesN)
      mfma_tile<ACo>(A, lda, K, W, bias, Cf, ldc, row0, jj << 6, lds);
  }
}

__global__ __launch_bounds__(BLOCK, 2) void ode_gru_kernel(KArgs a) {
  __shared__ __align__(16) _Float16 lds[CHUNK_HALFS];
  const int g  = blockIdx.x >> 4;
  const int jj = blockIdx.x & 15;
  unsigned* gb = a.bar + (g << 6);
  unsigned ep = 0;

  // ---- preamble: zero this group's h rows (ws is re-poisoned every call)
  for (int i = jj * BLOCK + threadIdx.x; i < 32 * Hz; i += GBLK * BLOCK)
    stc1(a.h + (size_t)g * 32 * Hz + i, 0.f);
  gbar(gb, jj, ++ep);

  const int row0 = g << 5;
  const int tn0  = ((jj & 7) << 1) | (jj >> 3);
  const int col0 = tn0 << 6;

  floatx4 K0 = {0,0,0,0}, K1 = {0,0,0,0}, K2 = {0,0,0,0};
  floatx4 K3 = {0,0,0,0}, K4 = {0,0,0,0}, Hc = {0,0,0,0};

  for (int s = 0; s < Sz; ++s) {
    if (s > 0) {
      const float dt = a.t[s] - a.t[s - 1];
      const float hs = dt * (1.0f / NSUB);
      for (int sub = 0; sub < NSUB; ++sub) {
        for (int st = 0; st < 6; ++st) {
          const float* yin = (st == 0) ? a.h : a.y;
          // L1 (tanh)
          mfma_tile_fast(yin, a.w0, a.b0, a.t1, 1, EPI_NONE, 0, 0.f,
                         nullptr, K0, K1, K2, K3, K4, Hc, row0, col0, lds);
          gbar(gb, jj, ++ep);
          // L2 (tanh)
          mfma_tile_fast(a.t1, a.w1, a.b1, a.t2, 1, EPI_NONE, 0, 0.f,
                         nullptr, K0, K1, K2, K3, K4, Hc, row0, col0, lds);
          gbar(gb, jj, ++ep);
          // L3 (linear) + fused dopri5 combine; k's stay in registers
          if (st < 5) {
            mfma_tile_fast(a.t2, a.w2, a.b2, a.y, 0, EPI_Y, st, hs,
                           a.h, K0, K1, K2, K3, K4, Hc, row0, col0, lds);
          } else {   // FSAL: h_next = y_6, in place
            mfma_tile_fast(a.t2, a.w2, a.b2, a.h, 0, EPI_H, 5, hs,
                           a.h, K0, K1, K2, K3, K4, Hc, row0, col0, lds);
          }
          gbar(gb, jj, ++ep);
        }
      }
    }

    // GRU gates (old path): gi = x_s@Wih^T+b ; gh = h@Whh^T+b
    run_phase<false>(a.x + (size_t)s * Dz, Sz * Dz, Dz, a.w_ih, a.b_ih, 3 * Hz,
                     a.gi, 3 * Hz, g, jj, lds);
    run_phase<true>(a.h, Hz, Hz, a.w_hh, a.b_hh, 3 * Hz,
                    a.gh, 3 * Hz, g, jj, lds);
    gbar(gb, jj, ++ep);

    // GRU pointwise, h in place (group-local rows)
    for (int i = jj * BLOCK + threadIdx.x; i < 32 * Hz; i += GBLK * BLOCK) {
      const int r = g * 32 + (i >> 10);
      const int c = i & (Hz - 1);
      const size_t gx = (size_t)r * 3 * Hz + c;
      const size_t hx = (size_t)r * Hz + c;
      const float ir  = ldc1(a.gi + gx);
      const float iz  = ldc1(a.gi + gx + Hz);
      const float inn = ldc1(a.gi + gx + 2 * Hz);
      const float hr  = ldc1(a.gh + gx);
      const float hzv = ldc1(a.gh + gx + Hz);
      const float hnn = ldc1(a.gh + gx + 2 * Hz);
      const float hv  = ldc1(a.h + hx);
      const float rr  = 1.f / (1.f + expf(-(ir + hr)));
      const float zz  = 1.f / (1.f + expf(-(iz + hzv)));
      const float nnv = tanhf(inn + rr * hnn);
      stc1(a.h + hx, (1.f - zz) * nnv + zz * hv);
    }
    gbar(gb, jj, ++ep);
  }

  // Final projections (old path, tilesN=2)
  run_phase<true>(a.h, Hz, Hz, a.mu_w, a.mu_b, Lz, a.out, Lz, g, jj, lds);
  run_phase<true>(a.h, Hz, Hz, a.lv_w, a.lv_b, Lz, a.out + (size_t)Bz * Lz,
                  Lz, g, jj, lds);
}

extern "C" void kernel_launch(void* const* d_in, const int* in_sizes, int n_in,
                              void* d_out, int out_size, void* d_ws, size_t ws_size,
                              hipStream_t stream) {
  KArgs a;
  a.x    = (const float*)d_in[0];
  a.t    = (const float*)d_in[1];
  a.w_ih = (const float*)d_in[2];
  a.w_hh = (const float*)d_in[3];
  a.b_ih = (const float*)d_in[4];
  a.b_hh = (const float*)d_in[5];
  a.w0   = (const float*)d_in[6];
  a.b0   = (const float*)d_in[7];
  a.w1   = (const float*)d_in[8];
  a.b1   = (const float*)d_in[9];
  a.w2   = (const float*)d_in[10];
  a.b2   = (const float*)d_in[11];
  a.mu_w = (const float*)d_in[12];
  a.mu_b = (const float*)d_in[13];
  a.lv_w = (const float*)d_in[14];
  a.lv_b = (const float*)d_in[15];
  a.out  = (float*)d_out;

  float* ws = (float*)d_ws;
  const size_t BH = (size_t)Bz * Hz;   // 524288 floats (2 MiB)
  a.h  = ws + 0 * BH;
  a.y  = ws + 1 * BH;
  a.t1 = ws + 2 * BH;
  a.t2 = ws + 3 * BH;
  a.gh = ws + 4 * BH;            // [512, 3072] = 3*BH -> ws+4BH..7BH
  a.gi = a.y;                    // y,t1,t2 dead during GRU phases (3*BH)
  a.bar = (unsigned*)(ws + 7 * BH);   // total ws use = 14 MiB + 4 KiB
  (void)ws_size; (void)in_sizes; (void)n_in; (void)out_size;

  KArgs args_val = a;
  void* params[] = { &args_val };
  hipLaunchCooperativeKernel((void*)ode_gru_kernel, dim3(GRID), dim3(BLOCK),
                             params, 0, stream);
}

// Round 9
// 191387.732 us; speedup vs baseline: 1.1844x; 1.1844x over previous
//
#include <hip/hip_runtime.h>
#include <math.h>

// Problem constants
#define Bz 512
#define Sz 128
#define Dz 128
#define Hz 1024
#define Lz 128
#define NSUB 4

#define GRID 256
#define BLOCK 512
#define NGRP 32   // 32 independent groups (16 batch rows each)
#define GBLK 8    // blocks per group; block tile = 16 rows x 128 cols

typedef _Float16 half8 __attribute__((ext_vector_type(8)));
typedef _Float16 half4v __attribute__((ext_vector_type(4)));
typedef float floatx4 __attribute__((ext_vector_type(4)));
typedef unsigned long long u64;

#define MFMA16(a, b, c) __builtin_amdgcn_mfma_f32_16x16x32_f16(a, b, c, 0, 0, 0)

// LDS: A only, frag-major. Chunk = 16 rows x 128 k: hi 2048 halfs + lo 2048
// halfs = 8 KB; double-buffered = 16 KB.
#define LDS_HALFS 8192

enum { EPI_NONE = 0, EPI_Y = 1, EPI_H = 2 };

// dopri5 tableau row i+1 (input coeffs of stage i+1). Row 5 == 5th-order b
// weights (FSAL): h_next = y_6; stage-7 f-eval is dead and skipped.
__constant__ float DPA_C[6][6] = {
  {0.2f, 0.f, 0.f, 0.f, 0.f, 0.f},
  {0.075f, 0.225f, 0.f, 0.f, 0.f, 0.f},
  {44.f/45.f, -56.f/15.f, 32.f/9.f, 0.f, 0.f, 0.f},
  {19372.f/6561.f, -25360.f/2187.f, 64448.f/6561.f, -212.f/729.f, 0.f, 0.f},
  {9017.f/3168.f, -355.f/33.f, 46732.f/5247.f, 49.f/176.f, -5103.f/18656.f, 0.f},
  {35.f/384.f, 0.f, 500.f/1113.f, 125.f/192.f, -2187.f/6784.f, 11.f/84.f},
};

struct KArgs {
  const float *x, *t, *w_ih, *w_hh, *b_ih, *b_hh;
  const float *w0, *b0, *w1, *b1, *w2, *b2, *mu_w, *mu_b, *lv_w, *lv_b;
  float* out;
  float *h, *y, *t1, *t2, *gi, *gh;
  unsigned* bar;
};

// ---- IF$-level (cross-XCD coherent) accesses: relaxed agent atomics bypass
// L1+L2, no cache-wiping fences. Weights (read-only inputs) use plain L2 loads.
__device__ __forceinline__ float2 ldc2(const float* p) {
  u64 v = __hip_atomic_load((u64*)p, __ATOMIC_RELAXED, __HIP_MEMORY_SCOPE_AGENT);
  union { u64 u; float2 f; } c; c.u = v; return c.f;
}
__device__ __forceinline__ float ldc1(const float* p) {
  unsigned v = __hip_atomic_load((unsigned*)p, __ATOMIC_RELAXED, __HIP_MEMORY_SCOPE_AGENT);
  union { unsigned u; float f; } c; c.u = v; return c.f;
}
__device__ __forceinline__ void stc1(float* p, float f) {
  union { float f; unsigned u; } c; c.f = f;
  __hip_atomic_store((unsigned*)p, c.u, __ATOMIC_RELAXED, __HIP_MEMORY_SCOPE_AGENT);
}

// Group barrier (8 blocks): equality-poll (poison-safe, no init needed).
// Producer waves drain stores (vmcnt) before signaling; relaxed flags ->
// no L2 invalidation anywhere.
__device__ __forceinline__ void gbar(unsigned* gb, int jj, unsigned e) {
  asm volatile("s_waitcnt vmcnt(0) lgkmcnt(0)" ::: "memory");
  __syncthreads();
  const int t = threadIdx.x;
  if (jj == 0) {
    if (t >= 1 && t < GBLK) {
      while (__hip_atomic_load(&gb[t], __ATOMIC_RELAXED, __HIP_MEMORY_SCOPE_AGENT) != e)
        __builtin_amdgcn_s_sleep(1);
    }
    __syncthreads();
    if (t == 0)
      __hip_atomic_store(&gb[32], e, __ATOMIC_RELAXED, __HIP_MEMORY_SCOPE_AGENT);
  } else {
    if (t == 0) {
      __hip_atomic_store(&gb[jj], e, __ATOMIC_RELAXED, __HIP_MEMORY_SCOPE_AGENT);
      while (__hip_atomic_load(&gb[32], __ATOMIC_RELAXED, __HIP_MEMORY_SCOPE_AGENT) != e)
        __builtin_amdgcn_s_sleep(1);
    }
    __syncthreads();
  }
}

__device__ __forceinline__ void split8(float4 a, float4 b, half8& h, half8& l) {
  float v[8] = {a.x, a.y, a.z, a.w, b.x, b.y, b.z, b.w};
#pragma unroll
  for (int i = 0; i < 8; ++i) {
    _Float16 hh = (_Float16)v[i];
    h[i] = hh;
    l[i] = (_Float16)((v[i] - (float)hh) * 2048.0f);
  }
}

// ---- One 16x128 tile of C[*,N] = A[*,K] @ W[N,K]^T + bias, K = NC*128.
// 8 waves = 8 distinct 16-col groups (no B duplication). A via IF$ ldc2 ->
// in-register hi/lo split -> frag-major LDS (conflict-free both directions).
// B: per-wave plain fp32 loads (read-only input, L2-cached) + in-reg split.
// 4 MFMA products recombined in fp32 (~2^-22 rel error).
template<int NC>
__device__ __forceinline__ void tile16(
    const float* __restrict__ Ab, int lda,
    const float* __restrict__ W, const float* __restrict__ bias,
    float* __restrict__ Yd, int ldc,
    int act, int epi, int stage, float hs,
    const float* __restrict__ hbuf,
    floatx4& K0, floatx4& K1, floatx4& K2, floatx4& K3, floatx4& K4,
    floatx4& Hc,
    int row0, int col0, _Float16* __restrict__ lds)
{
  const int tid = threadIdx.x;
  const int ln = tid & 63, l16 = ln & 15, qd = ln >> 4;
  const int wv = tid >> 6;                 // 0..7: col-group
  const int Kd = NC << 7;

  // A staging map: thread t covers frag positions 4t..4t+3 of the chunk
  // (frag (kq,ln,j): row = ln&15, k = kq*32 + (ln>>4)*8 + j)
  const int kqS = tid >> 7;                // 0..3
  const int w   = tid & 127;
  const int lnS = w >> 1;                  // 0..63
  const int jS  = (w & 1) << 2;            // 0 or 4
  const float* gAs = Ab + (size_t)(row0 + (lnS & 15)) * lda
                   + (kqS << 5) + (((lnS >> 4) & 3) << 3) + jS;
  const int sidx = tid << 2;               // hi halfs offset (0..2044)

  // B: wave's 16 cols
  const float* gBw = W + (size_t)(col0 + (wv << 4) + l16) * Kd + (qd << 3);

  float av[4];
  auto ldA = [&](int c) {
    float2 u = ldc2(gAs + (c << 7));
    float2 v2 = ldc2(gAs + (c << 7) + 2);
    av[0] = u.x; av[1] = u.y; av[2] = v2.x; av[3] = v2.y;
  };
  auto stA = [&](int buf) {
    half4v h, l;
#pragma unroll
    for (int i = 0; i < 4; ++i) {
      _Float16 hh = (_Float16)av[i];
      h[i] = hh;
      l[i] = (_Float16)((av[i] - (float)hh) * 2048.0f);
    }
    _Float16* d = lds + (buf << 12) + sidx;
    *(half4v*)d = h;
    *(half4v*)(d + 2048) = l;
  };
  float4 bq[2][8];
  auto ldBf = [&](int c, int pp) {
#pragma unroll
    for (int kq = 0; kq < 4; ++kq) {
      bq[pp][2 * kq]     = *(const float4*)(gBw + (c << 7) + (kq << 5));
      bq[pp][2 * kq + 1] = *(const float4*)(gBw + (c << 7) + (kq << 5) + 4);
    }
  };

  floatx4 Phh = {0,0,0,0}, Phl = {0,0,0,0}, Plh = {0,0,0,0}, Pll = {0,0,0,0};

  ldBf(0, 0);
  ldA(0);
  __syncthreads();               // prior tile's LDS readers done
  stA(0);
  if (NC > 1) ldA(1);

#pragma unroll
  for (int c = 0; c < NC; ++c) {
    __syncthreads();             // buf[c&1] stores visible; buf[c^1] free
    const int cur = c & 1;
    if (c + 1 < NC) {
      stA(cur ^ 1);              // regs (chunk c+1, loaded a full iter ago)
      if (c + 2 < NC) ldA(c + 2);
      ldBf(c + 1, cur ^ 1);      // next B in flight during this chunk
    }
    const _Float16* rb = lds + (cur << 12);
#pragma unroll
    for (int kq = 0; kq < 4; ++kq) {
      half8 bh, bl;
      split8(bq[cur][2 * kq], bq[cur][2 * kq + 1], bh, bl);
      const int ao = ((kq << 6) + ln) << 3;
      half8 ah = *(const half8*)(rb + ao);
      half8 al = *(const half8*)(rb + ao + 2048);
      Phh = MFMA16(ah, bh, Phh);
      Phl = MFMA16(ah, bl, Phl);
      Plh = MFMA16(al, bh, Plh);
      Pll = MFMA16(al, bl, Pll);
    }
  }

  // Epilogue. C/D layout: col = lane&15, row = (lane>>4)*4 + i (m89-verified)
  const int col   = col0 + (wv << 4) + l16;
  const int rbase = row0 + (qd << 2);
  const float bb = bias[col];
#pragma unroll
  for (int i = 0; i < 4; ++i) {
    float v = Phh[i] + (Phl[i] + Plh[i]) * (1.0f/2048.0f)
            + Pll[i] * (1.0f/4194304.0f) + bb;
    if (act) v = tanhf(v);
    const size_t off = (size_t)(rbase + i) * ldc + col;
    if (epi == EPI_NONE) {
      stc1(&Yd[off], v);
    } else {
      if (stage == 0) Hc[i] = ldc1(&hbuf[off]);
      float yv = Hc[i];
      const float* DP = DPA_C[stage];
      if (stage > 0) yv = fmaf(hs * DP[0], K0[i], yv);
      if (stage > 1) { float c1 = DP[1]; if (c1 != 0.f) yv = fmaf(hs * c1, K1[i], yv); }
      if (stage > 2) yv = fmaf(hs * DP[2], K2[i], yv);
      if (stage > 3) yv = fmaf(hs * DP[3], K3[i], yv);
      if (stage > 4) yv = fmaf(hs * DP[4], K4[i], yv);
      yv = fmaf(hs * DP[stage], v, yv);
      if      (stage == 0) K0[i] = v;
      else if (stage == 1) K1[i] = v;
      else if (stage == 2) K2[i] = v;
      else if (stage == 3) K3[i] = v;
      else if (stage == 4) K4[i] = v;
      stc1(&Yd[off], yv);        // y_{stage+1}, or h in place (FSAL, stage 5)
    }
  }
}

__global__ __launch_bounds__(BLOCK, 2) void ode_gru_kernel(KArgs a) {
  __shared__ __align__(16) _Float16 lds[LDS_HALFS];   // 16 KB
  const int g  = blockIdx.x >> 3;      // 0..31: group (16 batch rows)
  const int jj = blockIdx.x & 7;       // 0..7: col-tile (128 cols) in group
  unsigned* gb = a.bar + (g << 6);
  unsigned ep = 0;

  // ---- preamble: zero this group's h rows (ws is re-poisoned every call)
  for (int i = jj * BLOCK + threadIdx.x; i < 16 * Hz; i += GBLK * BLOCK)
    stc1(a.h + (size_t)g * 16 * Hz + i, 0.f);
  gbar(gb, jj, ++ep);

  const int row0 = g << 4;
  const int col0 = jj << 7;

  floatx4 K0 = {0,0,0,0}, K1 = {0,0,0,0}, K2 = {0,0,0,0};
  floatx4 K3 = {0,0,0,0}, K4 = {0,0,0,0}, Hc = {0,0,0,0};

  for (int s = 0; s < Sz; ++s) {
    if (s > 0) {
      const float dt = a.t[s] - a.t[s - 1];
      const float hs = dt * (1.0f / NSUB);
      for (int sub = 0; sub < NSUB; ++sub) {
        for (int st = 0; st < 6; ++st) {
          const float* yin = (st == 0) ? a.h : a.y;
          // L1 (tanh)
          tile16<8>(yin, Hz, a.w0, a.b0, a.t1, Hz, 1, EPI_NONE, 0, 0.f,
                    nullptr, K0, K1, K2, K3, K4, Hc, row0, col0, lds);
          gbar(gb, jj, ++ep);
          // L2 (tanh)
          tile16<8>(a.t1, Hz, a.w1, a.b1, a.t2, Hz, 1, EPI_NONE, 0, 0.f,
                    nullptr, K0, K1, K2, K3, K4, Hc, row0, col0, lds);
          gbar(gb, jj, ++ep);
          // L3 (linear) + fused dopri5 combine; k's stay in registers
          if (st < 5) {
            tile16<8>(a.t2, Hz, a.w2, a.b2, a.y, Hz, 0, EPI_Y, st, hs,
                      a.h, K0, K1, K2, K3, K4, Hc, row0, col0, lds);
          } else {   // FSAL: h_next = y_6, in place
            tile16<8>(a.t2, Hz, a.w2, a.b2, a.h, Hz, 0, EPI_H, 5, hs,
                      a.h, K0, K1, K2, K3, K4, Hc, row0, col0, lds);
          }
          gbar(gb, jj, ++ep);
        }
      }
    }

    // GRU gates: gi = x_s@Wih^T+b (K=128); gh = h@Whh^T+b (K=1024).
    // N=3072 -> 24 tiles of 128; each block does 3. One barrier after both.
#pragma unroll
    for (int i2 = 0; i2 < 3; ++i2)
      tile16<1>(a.x + (size_t)s * Dz, Sz * Dz, a.w_ih, a.b_ih, a.gi, 3 * Hz,
                0, EPI_NONE, 0, 0.f, nullptr,
                K0, K1, K2, K3, K4, Hc, row0, (jj + (i2 << 3)) << 7, lds);
#pragma unroll
    for (int i2 = 0; i2 < 3; ++i2)
      tile16<8>(a.h, Hz, a.w_hh, a.b_hh, a.gh, 3 * Hz,
                0, EPI_NONE, 0, 0.f, nullptr,
                K0, K1, K2, K3, K4, Hc, row0, (jj + (i2 << 3)) << 7, lds);
    gbar(gb, jj, ++ep);

    // GRU pointwise, h in place (group-local 16 rows)
    for (int i = jj * BLOCK + threadIdx.x; i < 16 * Hz; i += GBLK * BLOCK) {
      const int r = g * 16 + (i >> 10);
      const int c = i & (Hz - 1);
      const size_t gx = (size_t)r * 3 * Hz + c;
      const size_t hx = (size_t)r * Hz + c;
      const float ir  = ldc1(a.gi + gx);
      const float iz  = ldc1(a.gi + gx + Hz);
      const float inn = ldc1(a.gi + gx + 2 * Hz);
      const float hr  = ldc1(a.gh + gx);
      const float hzv = ldc1(a.gh + gx + Hz);
      const float hnn = ldc1(a.gh + gx + 2 * Hz);
      const float hv  = ldc1(a.h + hx);
      const float rr  = 1.f / (1.f + expf(-(ir + hr)));
      const float zz  = 1.f / (1.f + expf(-(iz + hzv)));
      const float nnv = tanhf(inn + rr * hnn);
      stc1(a.h + hx, (1.f - zz) * nnv + zz * hv);
    }
    gbar(gb, jj, ++ep);
  }

  // Final projections: N=128 = exactly one 16x128 tile per group.
  if (jj == 0)
    tile16<8>(a.h, Hz, a.mu_w, a.mu_b, a.out, Lz, 0, EPI_NONE, 0, 0.f,
              nullptr, K0, K1, K2, K3, K4, Hc, row0, 0, lds);
  if (jj == 1)
    tile16<8>(a.h, Hz, a.lv_w, a.lv_b, a.out + (size_t)Bz * Lz, Lz,
              0, EPI_NONE, 0, 0.f,
              nullptr, K0, K1, K2, K3, K4, Hc, row0, 0, lds);
}

extern "C" void kernel_launch(void* const* d_in, const int* in_sizes, int n_in,
                              void* d_out, int out_size, void* d_ws, size_t ws_size,
                              hipStream_t stream) {
  KArgs a;
  a.x    = (const float*)d_in[0];
  a.t    = (const float*)d_in[1];
  a.w_ih = (const float*)d_in[2];
  a.w_hh = (const float*)d_in[3];
  a.b_ih = (const float*)d_in[4];
  a.b_hh = (const float*)d_in[5];
  a.w0   = (const float*)d_in[6];
  a.b0   = (const float*)d_in[7];
  a.w1   = (const float*)d_in[8];
  a.b1   = (const float*)d_in[9];
  a.w2   = (const float*)d_in[10];
  a.b2   = (const float*)d_in[11];
  a.mu_w = (const float*)d_in[12];
  a.mu_b = (const float*)d_in[13];
  a.lv_w = (const float*)d_in[14];
  a.lv_b = (const float*)d_in[15];
  a.out  = (float*)d_out;

  float* ws = (float*)d_ws;
  const size_t BH = (size_t)Bz * Hz;   // 524288 floats (2 MiB)
  a.h  = ws + 0 * BH;
  a.y  = ws + 1 * BH;
  a.t1 = ws + 2 * BH;
  a.t2 = ws + 3 * BH;
  a.gh = ws + 4 * BH;            // [512, 3072] = 3*BH -> ws+4BH..7BH
  a.gi = a.y;                    // y,t1,t2 dead during GRU phases (3*BH)
  a.bar = (unsigned*)(ws + 7 * BH);   // 32 groups x 64 u32; total 14 MiB + 8 KiB
  (void)ws_size; (void)in_sizes; (void)n_in; (void)out_size;

  KArgs args_val = a;
  void* params[] = { &args_val };
  hipLaunchCooperativeKernel((void*)ode_gru_kernel, dim3(GRID), dim3(BLOCK),
                             params, 0, stream);
}

// Round 10
// 178941.003 us; speedup vs baseline: 1.2668x; 1.0696x over previous
//
#include <hip/hip_runtime.h>
#include <math.h>

// Problem constants
#define Bz 512
#define Sz 128
#define Dz 128
#define Hz 1024
#define Lz 128
#define NSUB 4

#define GRID 256
#define BLOCK 512
#define NGRP 32   // 32 independent groups (16 batch rows each)
#define GBLK 8    // blocks per group; block tile = 16 rows x 128 cols

typedef _Float16 half8 __attribute__((ext_vector_type(8)));
typedef _Float16 half4v __attribute__((ext_vector_type(4)));
typedef float floatx4 __attribute__((ext_vector_type(4)));
typedef unsigned long long u64;

#define MFMA16(a, b, c) __builtin_amdgcn_mfma_f32_16x16x32_f16(a, b, c, 0, 0, 0)

// LDS: A only, frag-major. Chunk = 16 rows x 128 k: hi 2048 + lo 2048 halfs
// = 8 KB; double-buffered = 16 KB. Conflict-free (R9-measured: 0 conflicts).
#define LDS_HALFS 8192

enum { EPI_NONE = 0, EPI_Y = 1, EPI_H = 2 };

// dopri5 tableau row i+1 (input coeffs of stage i+1). Row 5 == 5th-order b
// weights (FSAL): h_next = y_6; stage-7 f-eval is dead and skipped.
__constant__ float DPA_C[6][6] = {
  {0.2f, 0.f, 0.f, 0.f, 0.f, 0.f},
  {0.075f, 0.225f, 0.f, 0.f, 0.f, 0.f},
  {44.f/45.f, -56.f/15.f, 32.f/9.f, 0.f, 0.f, 0.f},
  {19372.f/6561.f, -25360.f/2187.f, 64448.f/6561.f, -212.f/729.f, 0.f, 0.f},
  {9017.f/3168.f, -355.f/33.f, 46732.f/5247.f, 49.f/176.f, -5103.f/18656.f, 0.f},
  {35.f/384.f, 0.f, 500.f/1113.f, 125.f/192.f, -2187.f/6784.f, 11.f/84.f},
};

struct KArgs {
  const float *x, *t, *w_ih, *w_hh, *b_ih, *b_hh;
  const float *w0, *b0, *w1, *b1, *w2, *b2, *mu_w, *mu_b, *lv_w, *lv_b;
  float* out;
  float *h, *y, *t1, *t2, *gi, *gh;
  unsigned* bar;
};

// ---- IF$-level (cross-XCD coherent) accesses: relaxed agent atomics bypass
// L1+L2, no cache-wiping fences. Weights (read-only inputs) use plain L2 loads.
__device__ __forceinline__ float2 ldc2(const float* p) {
  u64 v = __hip_atomic_load((u64*)p, __ATOMIC_RELAXED, __HIP_MEMORY_SCOPE_AGENT);
  union { u64 u; float2 f; } c; c.u = v; return c.f;
}
__device__ __forceinline__ float ldc1(const float* p) {
  unsigned v = __hip_atomic_load((unsigned*)p, __ATOMIC_RELAXED, __HIP_MEMORY_SCOPE_AGENT);
  union { unsigned u; float f; } c; c.u = v; return c.f;
}
__device__ __forceinline__ void stc1(float* p, float f) {
  union { float f; unsigned u; } c; c.f = f;
  __hip_atomic_store((unsigned*)p, c.u, __ATOMIC_RELAXED, __HIP_MEMORY_SCOPE_AGENT);
}

// Symmetric group barrier (8 blocks): each block release-stores its epoch to
// its slot, then ALL blocks poll the single 64B line holding all 8 slots (one
// coalesced sector read by lanes 0..7). No leader round-trip (saves ~1 MALL
// RTT vs R9). Window poll (v-e)>1 -> wait: tolerates neighbors one barrier
// ahead (they can't be 2 ahead: they'd be waiting on us), and the 0xAA poison
// (v-e huge) also waits => poison-safe, no init needed.
__device__ __forceinline__ void gbar(unsigned* gb, int jj, unsigned e) {
  asm volatile("s_waitcnt vmcnt(0) lgkmcnt(0)" ::: "memory");
  __syncthreads();
  const int t = threadIdx.x;
  if (t == 0)
    __hip_atomic_store(&gb[jj], e, __ATOMIC_RELAXED, __HIP_MEMORY_SCOPE_AGENT);
  if (t < GBLK) {
    while (__hip_atomic_load(&gb[t], __ATOMIC_RELAXED, __HIP_MEMORY_SCOPE_AGENT) - e > 1u)
      __builtin_amdgcn_s_sleep(1);
  }
  __syncthreads();
}

__device__ __forceinline__ void split8(float4 a, float4 b, half8& h, half8& l) {
  float v[8] = {a.x, a.y, a.z, a.w, b.x, b.y, b.z, b.w};
#pragma unroll
  for (int i = 0; i < 8; ++i) {
    _Float16 hh = (_Float16)v[i];
    h[i] = hh;
    l[i] = (_Float16)((v[i] - (float)hh) * 2048.0f);
  }
}

// ---- One 16x128 tile of C[*,N] = A[*,K] @ W[N,K]^T + bias, K = NC*128.
// 8 waves = 8 distinct 16-col groups (no B duplication). A via IF$ ldc2 ->
// in-register hi/lo split -> frag-major LDS (conflict-free both directions).
// ALL NC chunks' A-loads issued up front (MALL latency paid once, not 8x).
// B: per-wave plain fp32 loads (read-only input, L2-cached) + in-reg split.
// 4 MFMA products recombined in fp32 (~2^-22 rel error).
template<int NC>
__device__ __forceinline__ void tile16(
    const float* __restrict__ Ab, int lda,
    const float* __restrict__ W, const float* __restrict__ bias,
    float* __restrict__ Yd, int ldc,
    int act, int epi, int stage, float hs,
    const float* __restrict__ hbuf,
    floatx4& K0, floatx4& K1, floatx4& K2, floatx4& K3, floatx4& K4,
    floatx4& Hc,
    int row0, int col0, _Float16* __restrict__ lds)
{
  const int tid = threadIdx.x;
  const int ln = tid & 63, l16 = ln & 15, qd = ln >> 4;
  const int wv = tid >> 6;                 // 0..7: col-group
  const int Kd = NC << 7;

  // A staging map: thread t covers frag positions 4t..4t+3 of the chunk
  // (frag (kq,ln,j): row = ln&15, k = kq*32 + (ln>>4)*8 + j)
  const int kqS = tid >> 7;                // 0..3
  const int w   = tid & 127;
  const int lnS = w >> 1;                  // 0..63
  const int jS  = (w & 1) << 2;            // 0 or 4
  const float* gAs = Ab + (size_t)(row0 + (lnS & 15)) * lda
                   + (kqS << 5) + (((lnS >> 4) & 3) << 3) + jS;
  const int sidx = tid << 2;               // hi halfs offset (0..2044)

  // B: wave's 16 cols
  const float* gBw = W + (size_t)(col0 + (wv << 4) + l16) * Kd + (qd << 3);

  float av[NC][4];
  auto ldA = [&](int c) {
    float2 u  = ldc2(gAs + (c << 7));
    float2 v2 = ldc2(gAs + (c << 7) + 2);
    av[c][0] = u.x; av[c][1] = u.y; av[c][2] = v2.x; av[c][3] = v2.y;
  };
  auto stA = [&](int buf, int c) {
    half4v h, l;
#pragma unroll
    for (int i = 0; i < 4; ++i) {
      _Float16 hh = (_Float16)av[c][i];
      h[i] = hh;
      l[i] = (_Float16)((av[c][i] - (float)hh) * 2048.0f);
    }
    _Float16* d = lds + (buf << 12) + sidx;
    *(half4v*)d = h;
    *(half4v*)(d + 2048) = l;
  };
  float4 bq[2][8];
  auto ldBf = [&](int c, int pp) {
#pragma unroll
    for (int kq = 0; kq < 4; ++kq) {
      bq[pp][2 * kq]     = *(const float4*)(gBw + (c << 7) + (kq << 5));
      bq[pp][2 * kq + 1] = *(const float4*)(gBw + (c << 7) + (kq << 5) + 4);
    }
  };

  floatx4 Phh = {0,0,0,0}, Phl = {0,0,0,0}, Plh = {0,0,0,0}, Pll = {0,0,0,0};

  ldBf(0, 0);                    // B chunk 0 (L2) in flight first
#pragma unroll
  for (int c = 0; c < NC; ++c)   // ALL A chunks in flight (one latency window)
    ldA(c);
  __syncthreads();               // prior tile's LDS readers done
  stA(0, 0);

#pragma unroll
  for (int c = 0; c < NC; ++c) {
    __syncthreads();             // buf[c&1] stores visible; buf[c^1] free
    const int cur = c & 1;
    if (c + 1 < NC) {
      stA(cur ^ 1, c + 1);       // regs (already resident) -> other buffer
      ldBf(c + 1, cur ^ 1);      // next B in flight during this chunk
    }
    const _Float16* rb = lds + (cur << 12);
#pragma unroll
    for (int kq = 0; kq < 4; ++kq) {
      half8 bh, bl;
      split8(bq[cur][2 * kq], bq[cur][2 * kq + 1], bh, bl);
      const int ao = ((kq << 6) + ln) << 3;
      half8 ah = *(const half8*)(rb + ao);
      half8 al = *(const half8*)(rb + ao + 2048);
      Phh = MFMA16(ah, bh, Phh);
      Phl = MFMA16(ah, bl, Phl);
      Plh = MFMA16(al, bh, Plh);
      Pll = MFMA16(al, bl, Pll);
    }
  }

  // Epilogue. C/D layout: col = lane&15, row = (lane>>4)*4 + i (m89-verified)
  const int col   = col0 + (wv << 4) + l16;
  const int rbase = row0 + (qd << 2);
  const float bb = bias[col];
#pragma unroll
  for (int i = 0; i < 4; ++i) {
    float v = Phh[i] + (Phl[i] + Plh[i]) * (1.0f/2048.0f)
            + Pll[i] * (1.0f/4194304.0f) + bb;
    if (act) v = tanhf(v);
    const size_t off = (size_t)(rbase + i) * ldc + col;
    if (epi == EPI_NONE) {
      stc1(&Yd[off], v);
    } else {
      if (stage == 0) Hc[i] = ldc1(&hbuf[off]);
      float yv = Hc[i];
      const float* DP = DPA_C[stage];
      if (stage > 0) yv = fmaf(hs * DP[0], K0[i], yv);
      if (stage > 1) { float c1 = DP[1]; if (c1 != 0.f) yv = fmaf(hs * c1, K1[i], yv); }
      if (stage > 2) yv = fmaf(hs * DP[2], K2[i], yv);
      if (stage > 3) yv = fmaf(hs * DP[3], K3[i], yv);
      if (stage > 4) yv = fmaf(hs * DP[4], K4[i], yv);
      yv = fmaf(hs * DP[stage], v, yv);
      if      (stage == 0) K0[i] = v;
      else if (stage == 1) K1[i] = v;
      else if (stage == 2) K2[i] = v;
      else if (stage == 3) K3[i] = v;
      else if (stage == 4) K4[i] = v;
      stc1(&Yd[off], yv);        // y_{stage+1}, or h in place (FSAL, stage 5)
    }
  }
}

__global__ __launch_bounds__(BLOCK, 2) void ode_gru_kernel(KArgs a) {
  __shared__ __align__(16) _Float16 lds[LDS_HALFS];   // 16 KB
  const int g  = blockIdx.x >> 3;      // 0..31: group (16 batch rows)
  const int jj = blockIdx.x & 7;       // 0..7: col-tile (128 cols) in group
  unsigned* gb = a.bar + (g << 6);
  unsigned ep = 0;

  // ---- preamble: zero this group's h rows (ws is re-poisoned every call)
  for (int i = jj * BLOCK + threadIdx.x; i < 16 * Hz; i += GBLK * BLOCK)
    stc1(a.h + (size_t)g * 16 * Hz + i, 0.f);
  gbar(gb, jj, ++ep);

  const int row0 = g << 4;
  const int col0 = jj << 7;

  floatx4 K0 = {0,0,0,0}, K1 = {0,0,0,0}, K2 = {0,0,0,0};
  floatx4 K3 = {0,0,0,0}, K4 = {0,0,0,0}, Hc = {0,0,0,0};

  for (int s = 0; s < Sz; ++s) {
    if (s > 0) {
      const float dt = a.t[s] - a.t[s - 1];
      const float hs = dt * (1.0f / NSUB);
      for (int sub = 0; sub < NSUB; ++sub) {
        for (int st = 0; st < 6; ++st) {
          const float* yin = (st == 0) ? a.h : a.y;
          // L1 (tanh)
          tile16<8>(yin, Hz, a.w0, a.b0, a.t1, Hz, 1, EPI_NONE, 0, 0.f,
                    nullptr, K0, K1, K2, K3, K4, Hc, row0, col0, lds);
          gbar(gb, jj, ++ep);
          // L2 (tanh)
          tile16<8>(a.t1, Hz, a.w1, a.b1, a.t2, Hz, 1, EPI_NONE, 0, 0.f,
                    nullptr, K0, K1, K2, K3, K4, Hc, row0, col0, lds);
          gbar(gb, jj, ++ep);
          // L3 (linear) + fused dopri5 combine; k's stay in registers
          if (st < 5) {
            tile16<8>(a.t2, Hz, a.w2, a.b2, a.y, Hz, 0, EPI_Y, st, hs,
                      a.h, K0, K1, K2, K3, K4, Hc, row0, col0, lds);
          } else {   // FSAL: h_next = y_6, in place
            tile16<8>(a.t2, Hz, a.w2, a.b2, a.h, Hz, 0, EPI_H, 5, hs,
                      a.h, K0, K1, K2, K3, K4, Hc, row0, col0, lds);
          }
          gbar(gb, jj, ++ep);
        }
      }
    }

    // GRU gates: gi = x_s@Wih^T+b (K=128); gh = h@Whh^T+b (K=1024).
    // N=3072 -> 24 tiles of 128; each block does 3. One barrier after both.
#pragma unroll
    for (int i2 = 0; i2 < 3; ++i2)
      tile16<1>(a.x + (size_t)s * Dz, Sz * Dz, a.w_ih, a.b_ih, a.gi, 3 * Hz,
                0, EPI_NONE, 0, 0.f, nullptr,
                K0, K1, K2, K3, K4, Hc, row0, (jj + (i2 << 3)) << 7, lds);
#pragma unroll
    for (int i2 = 0; i2 < 3; ++i2)
      tile16<8>(a.h, Hz, a.w_hh, a.b_hh, a.gh, 3 * Hz,
                0, EPI_NONE, 0, 0.f, nullptr,
                K0, K1, K2, K3, K4, Hc, row0, (jj + (i2 << 3)) << 7, lds);
    gbar(gb, jj, ++ep);

    // GRU pointwise, h in place (group-local 16 rows)
    for (int i = jj * BLOCK + threadIdx.x; i < 16 * Hz; i += GBLK * BLOCK) {
      const int r = g * 16 + (i >> 10);
      const int c = i & (Hz - 1);
      const size_t gx = (size_t)r * 3 * Hz + c;
      const size_t hx = (size_t)r * Hz + c;
      const float ir  = ldc1(a.gi + gx);
      const float iz  = ldc1(a.gi + gx + Hz);
      const float inn = ldc1(a.gi + gx + 2 * Hz);
      const float hr  = ldc1(a.gh + gx);
      const float hzv = ldc1(a.gh + gx + Hz);
      const float hnn = ldc1(a.gh + gx + 2 * Hz);
      const float hv  = ldc1(a.h + hx);
      const float rr  = 1.f / (1.f + expf(-(ir + hr)));
      const float zz  = 1.f / (1.f + expf(-(iz + hzv)));
      const float nnv = tanhf(inn + rr * hnn);
      stc1(a.h + hx, (1.f - zz) * nnv + zz * hv);
    }
    gbar(gb, jj, ++ep);
  }

  // Final projections: N=128 = exactly one 16x128 tile per group.
  if (jj == 0)
    tile16<8>(a.h, Hz, a.mu_w, a.mu_b, a.out, Lz, 0, EPI_NONE, 0, 0.f,
              nullptr, K0, K1, K2, K3, K4, Hc, row0, 0, lds);
  if (jj == 1)
    tile16<8>(a.h, Hz, a.lv_w, a.lv_b, a.out + (size_t)Bz * Lz, Lz,
              0, EPI_NONE, 0, 0.f,
              nullptr, K0, K1, K2, K3, K4, Hc, row0, 0, lds);
}

extern "C" void kernel_launch(void* const* d_in, const int* in_sizes, int n_in,
                              void* d_out, int out_size, void* d_ws, size_t ws_size,
                              hipStream_t stream) {
  KArgs a;
  a.x    = (const float*)d_in[0];
  a.t    = (const float*)d_in[1];
  a.w_ih = (const float*)d_in[2];
  a.w_hh = (const float*)d_in[3];
  a.b_ih = (const float*)d_in[4];
  a.b_hh = (const float*)d_in[5];
  a.w0   = (const float*)d_in[6];
  a.b0   = (const float*)d_in[7];
  a.w1   = (const float*)d_in[8];
  a.b1   = (const float*)d_in[9];
  a.w2   = (const float*)d_in[10];
  a.b2   = (const float*)d_in[11];
  a.mu_w = (const float*)d_in[12];
  a.mu_b = (const float*)d_in[13];
  a.lv_w = (const float*)d_in[14];
  a.lv_b = (const float*)d_in[15];
  a.out  = (float*)d_out;

  float* ws = (float*)d_ws;
  const size_t BH = (size_t)Bz * Hz;   // 524288 floats (2 MiB)
  a.h  = ws + 0 * BH;
  a.y  = ws + 1 * BH;
  a.t1 = ws + 2 * BH;
  a.t2 = ws + 3 * BH;
  a.gh = ws + 4 * BH;            // [512, 3072] = 3*BH -> ws+4BH..7BH
  a.gi = a.y;                    // y,t1,t2 dead during GRU phases (3*BH)
  a.bar = (unsigned*)(ws + 7 * BH);   // 32 groups x 64 u32; total 14 MiB + 8 KiB
  (void)ws_size; (void)in_sizes; (void)n_in; (void)out_size;

  KArgs args_val = a;
  void* params[] = { &args_val };
  hipLaunchKernelGGL(ode_gru_kernel, dim3(GRID), dim3(BLOCK), 0, stream, a);
  (void)params;
}